// Round 1
// baseline (516.301 us; speedup 1.0000x reference)
//
#include <hip/hip_runtime.h>

// CompanionSSM: y = causal_conv(u, k) with k[h,l] = c_h^T A_h^l b_h, A = companion(a_n).
// Implemented as chunked state-space scan (C=64):
//   Y_chunk = W@S + LowerToeplitz(k)@U ;  S' = T@S + V@U
// with per-head precomputed T=A^64, V[:,m]=A^{63-m}b, W[j,:]=c^T A^{j+1}, k[j]=c^T A^j b.

#define NKH 256          // heads
#define KD  64           // state dim / companion order
#define NB  4            // batch
#define SL  4096         // sequence length
#define DM  1024         // model dim
#define CHK 64           // chunk length
#define NCHUNK (SL/CHK)  // 64
#define HEAD_WS (3*KD*KD + KD)   // floats per head in workspace: Tt,Vt,Wt,k

// ---------------------------------------------------------------- prep ----
// One wave per head. Companion apply: (A v)[i] = v[i-1] + a_n[i]*v[63].
__global__ __launch_bounds__(64) void prep_kernel(
    const float* __restrict__ ga, const float* __restrict__ gb,
    const float* __restrict__ gc, float* __restrict__ ws)
{
  const int h = blockIdx.x;
  const int i = threadIdx.x;

  const float av = ga[h*KD + i];
  float nrm = fabsf(av);
#pragma unroll
  for (int off = 32; off; off >>= 1) nrm += __shfl_xor(nrm, off, 64);
  // mean(|row-sums|) ~ 51 >> 1e-4 for this problem's N(0,1) inputs -> always normalize
  const float an = av / nrm;
  const float bv = gb[h*KD + i];
  const float cv = gc[h*KD + i];

  float* Tt = ws + (size_t)h * HEAD_WS;   // Tt[m][r] = T[r][m]
  float* Vt = Tt + KD*KD;                 // Vt[m][r] = V[r][m]
  float* Wt = Vt + KD*KD;                 // Wt[m][j] = W[j][m]
  float* kv = Wt + KD*KD;                 // k[0..63]

  // v_j = A^j b :  Vt[m][:] = v_{63-m} ;  k[j] = dot(c, v_j)
  float v = bv;
  for (int j = 0; j < KD; ++j) {
    float d = cv * v;
#pragma unroll
    for (int off = 32; off; off >>= 1) d += __shfl_xor(d, off, 64);
    if (i == 0) kv[j] = d;
    Vt[(KD-1-j)*KD + i] = v;
    const float top = __shfl(v, KD-1, 64);
    const float vm1 = __shfl_up(v, 1, 64);
    v = (i > 0 ? vm1 : 0.0f) + an * top;
  }

  // T = A^64; column m of T is A^m a_n  (since A^64 e_m = A^{64+m} e_0, A^64 e_0 = a_n)
  float tt = an;
  for (int m = 0; m < KD; ++m) {
    Tt[m*KD + i] = tt;
    const float top = __shfl(tt, KD-1, 64);
    const float tm1 = __shfl_up(tt, 1, 64);
    tt = (i > 0 ? tm1 : 0.0f) + an * top;
  }

  // w_{j+1} = A^T w_j, w_0 = c :  (A^T w)[i] = w[i+1] (i<63), dot(a_n,w) (i=63)
  // W[j][:] = w_{j+1}
  float w = cv;
  for (int j = 0; j < KD; ++j) {
    float d = an * w;
#pragma unroll
    for (int off = 32; off; off >>= 1) d += __shfl_xor(d, off, 64);
    const float wp1 = __shfl_down(w, 1, 64);
    w = (i < KD-1) ? wp1 : d;
    Wt[i*KD + j] = w;   // scattered store; prep is tiny
  }
}

// ---------------------------------------------------------------- scan ----
// One block per head. 16 channels/head (4 batch x 4 d-lanes). 64 sequential chunks.
// Threads 0..127  : Y tiles, 2 rows x 4 ch, full K
// Threads 128..255: S' tiles, 4 rows x 4 ch, K split in 2 halves (combine via sP)
__global__ __launch_bounds__(256) void scan_kernel(
    const float* __restrict__ u, const float* __restrict__ ws,
    float* __restrict__ out)
{
  __shared__ __align__(16) float smat[HEAD_WS];   // Tt,Vt,Wt,k  (48.25 KB)
  __shared__ __align__(16) float sS[KD*16];       // state  [m][ch]
  __shared__ __align__(16) float sU[CHK*16];      // inputs [m][ch]
  __shared__ __align__(16) float sP[64*16];       // S' half-1 partials

  const int h = blockIdx.x;
  const int t = threadIdx.x;

  const float* wsh = ws + (size_t)h * HEAD_WS;
  for (int idx = t; idx < HEAD_WS/4; idx += 256)
    ((float4*)smat)[idx] = ((const float4*)wsh)[idx];

  const float* sTt = smat;
  const float* sVt = smat + KD*KD;
  const float* sWt = smat + 2*KD*KD;
  const float* skv = smat + 3*KD*KD;

#pragma unroll
  for (int k2 = 0; k2 < 4; ++k2) sS[t + 256*k2] = 0.0f;

  const bool isY = (t < 128);
  const int yr0  = (t >> 2) * 2;          // Y rows (when isY)
  const int ych0 = (t & 3) * 4;           // Y channels
  const int sidx = t - 128;
  const int stile = sidx & 63;
  const int shalf = (sidx >> 6) & 1;
  const int sr0  = (stile >> 2) * 4;      // S' rows
  const int sch0 = (stile & 3) * 4;       // S' channels
  const int smlo = shalf * 32;

  const int um = t >> 2;                  // U staging: row m
  const int ub = t & 3;                   // U staging: batch

  float acc[4][4];

#pragma unroll 1
  for (int q = 0; q < NCHUNK; ++q) {
    // stage U chunk: sU[m][b*4+dd] = u[b][q*64+m][4h+dd]
    {
      const float4 uv = *(const float4*)(u + ((size_t)ub*SL + (size_t)(q*CHK + um))*DM + h*4);
      *(float4*)(sU + um*16 + ub*4) = uv;
    }
    __syncthreads();   // B1: U staged, S from previous chunk visible

#pragma unroll
    for (int r = 0; r < 4; ++r)
#pragma unroll
      for (int c2 = 0; c2 < 4; ++c2) acc[r][c2] = 0.0f;

    if (isY) {
#pragma unroll 4
      for (int m = 0; m < CHK; ++m) {
        const float2 wv = *(const float2*)(sWt + m*KD + yr0);
        const float4 sv = *(const float4*)(sS + m*16 + ych0);
        const float4 uv = *(const float4*)(sU + m*16 + ych0);
        float kc0 = skv[(yr0     - m) & (KD-1)]; kc0 = (m <= yr0    ) ? kc0 : 0.0f;
        float kc1 = skv[(yr0 + 1 - m) & (KD-1)]; kc1 = (m <= yr0 + 1) ? kc1 : 0.0f;
        const float sc[4] = {sv.x, sv.y, sv.z, sv.w};
        const float uc[4] = {uv.x, uv.y, uv.z, uv.w};
#pragma unroll
        for (int c2 = 0; c2 < 4; ++c2) {
          acc[0][c2] += wv.x * sc[c2] + kc0 * uc[c2];
          acc[1][c2] += wv.y * sc[c2] + kc1 * uc[c2];
        }
      }
    } else {
#pragma unroll 4
      for (int mm = 0; mm < 32; ++mm) {
        const int m = smlo + mm;
        const float4 tv = *(const float4*)(sTt + m*KD + sr0);
        const float4 vv = *(const float4*)(sVt + m*KD + sr0);
        const float4 sv = *(const float4*)(sS + m*16 + sch0);
        const float4 uv = *(const float4*)(sU + m*16 + sch0);
        const float tr[4] = {tv.x, tv.y, tv.z, tv.w};
        const float vr[4] = {vv.x, vv.y, vv.z, vv.w};
        const float sc[4] = {sv.x, sv.y, sv.z, sv.w};
        const float uc[4] = {uv.x, uv.y, uv.z, uv.w};
#pragma unroll
        for (int r = 0; r < 4; ++r)
#pragma unroll
          for (int c2 = 0; c2 < 4; ++c2)
            acc[r][c2] += tr[r] * sc[c2] + vr[r] * uc[c2];
      }
      if (shalf) {
#pragma unroll
        for (int r = 0; r < 4; ++r)
          *(float4*)(sP + stile*16 + r*4) =
            make_float4(acc[r][0], acc[r][1], acc[r][2], acc[r][3]);
      }
    }
    __syncthreads();   // B2: compute done, partials in sP

    if (isY) {
      const size_t o0 = ((size_t)(t & 3)*SL + (size_t)(q*CHK + yr0))*DM + h*4;
      *(float4*)(out + o0)      = make_float4(acc[0][0], acc[0][1], acc[0][2], acc[0][3]);
      *(float4*)(out + o0 + DM) = make_float4(acc[1][0], acc[1][1], acc[1][2], acc[1][3]);
    } else if (!shalf) {
      // combine halves and commit new state (next read is after next B1)
#pragma unroll
      for (int r = 0; r < 4; ++r) {
        const float4 pv = *(const float4*)(sP + stile*16 + r*4);
        *(float4*)(sS + (sr0 + r)*16 + sch0) =
          make_float4(acc[r][0] + pv.x, acc[r][1] + pv.y,
                      acc[r][2] + pv.z, acc[r][3] + pv.w);
      }
    }
  }
}

// ---------------------------------------------------------------- launch --
extern "C" void kernel_launch(void* const* d_in, const int* in_sizes, int n_in,
                              void* d_out, int out_size, void* d_ws, size_t ws_size,
                              hipStream_t stream)
{
  const float* u = (const float*)d_in[0];
  const float* a = (const float*)d_in[1];
  const float* b = (const float*)d_in[2];
  const float* c = (const float*)d_in[3];
  float* ws  = (float*)d_ws;     // needs 256*12352*4 = 12.6 MB
  float* out = (float*)d_out;

  prep_kernel<<<NKH, KD, 0, stream>>>(a, b, c, ws);
  scan_kernel<<<NKH, 256, 0, stream>>>(u, ws, out);
}

// Round 2
// 213.968 us; speedup vs baseline: 2.4130x; 2.4130x over previous
//
#include <hip/hip_runtime.h>

// CompanionSSM via chunked state-space scan, bf16 MFMA formulation.
// Per head: G (128x128, constant) = [[W, ToeplitzK],[T, V]], per chunk:
//   Z(128x16) = G @ X,  X = [S(64x16); U(64x16)]
//   Z rows 0..63  = Y chunk outputs -> global
//   Z rows 64..127= S' -> next chunk's X (LDS round-trip, parity double-buffer)
// A-fragments of G live in registers for the whole kernel (G is chunk-invariant).

#define NKH 256
#define KD  64
#define SL  4096
#define DM  1024
#define NCHUNK 64
#define XSTR 200      // X row stride in bf16 units (16B-aligned, 2-way banks)
#define YSTR 20       // sY row stride in floats

typedef __attribute__((ext_vector_type(8))) short short8;
typedef __attribute__((ext_vector_type(4))) float floatx4;

static __device__ __forceinline__ unsigned short f2bf(float x) {
  union { float f; unsigned u; } v; v.f = x;
  return (unsigned short)((v.u + 0x7FFFu + ((v.u >> 16) & 1u)) >> 16);
}

// ---------------------------------------------------------------- prep ----
// One wave per head; emits G[128][128] in bf16 (row-major) to ws.
__global__ __launch_bounds__(64) void prep_kernel(
    const float* __restrict__ ga, const float* __restrict__ gb,
    const float* __restrict__ gc, unsigned short* __restrict__ gw)
{
  __shared__ unsigned short G[128 * 128];   // 32 KB
  __shared__ float kv[KD];

  const int h = blockIdx.x;
  const int i = threadIdx.x;

  const float av = ga[h*KD + i];
  float nrm = fabsf(av);
#pragma unroll
  for (int off = 32; off; off >>= 1) nrm += __shfl_xor(nrm, off, 64);
  const float an = av / nrm;          // mean(|rowsum|) >> eps for N(0,1) inputs
  const float bv = gb[h*KD + i];
  const float cv = gc[h*KD + i];

  // V & k:  v_j = A^j b.  V[r][m] = (A^{63-m} b)[r] -> G[64+i][64+63-j]; k[j]=c.v_j
  float v = bv;
  for (int j = 0; j < KD; ++j) {
    float d = cv * v;
#pragma unroll
    for (int off = 32; off; off >>= 1) d += __shfl_xor(d, off, 64);
    if (i == 0) kv[j] = d;
    G[(64+i)*128 + 64 + (63-j)] = f2bf(v);
    const float top = __shfl(v, KD-1, 64);
    const float vm1 = __shfl_up(v, 1, 64);
    v = (i > 0 ? vm1 : 0.0f) + an * top;
  }

  // T = A^64, col m = A^m a_n -> G[64+i][m]
  float tt = an;
  for (int m = 0; m < KD; ++m) {
    G[(64+i)*128 + m] = f2bf(tt);
    const float top = __shfl(tt, KD-1, 64);
    const float tm1 = __shfl_up(tt, 1, 64);
    tt = (i > 0 ? tm1 : 0.0f) + an * top;
  }

  // W rows: w_{j+1} = A^T w_j, w_0 = c -> G[j][i]
  float w = cv;
  for (int j = 0; j < KD; ++j) {
    float d = an * w;
#pragma unroll
    for (int off = 32; off; off >>= 1) d += __shfl_xor(d, off, 64);
    const float wp1 = __shfl_down(w, 1, 64);
    w = (i < KD-1) ? wp1 : d;
    G[j*128 + i] = f2bf(w);
  }

  __syncthreads();   // kv visible

  // Toeplitz block: G[i][64+m] = k[i-m] for m<=i else 0
  for (int m = 0; m < KD; ++m)
    G[i*128 + 64 + m] = (m <= i) ? f2bf(kv[i-m]) : (unsigned short)0;

  __syncthreads();

  // coalesced copy out: 2048 int4
  const int4* src = (const int4*)G;
  int4* dst = (int4*)(gw + (size_t)h * 16384);
  for (int idx = i; idx < 2048; idx += 64) dst[idx] = src[idx];
}

// ---------------------------------------------------------------- scan ----
// One block (4 waves) per head. Chunk loop: stage U -> B-frags -> 8 MFMA ->
// waves 0-1 emit Y (via sY transpose), waves 2-3 emit S' into X parity buffer.
__global__ __launch_bounds__(256) void scan_kernel(
    const float* __restrict__ u, const unsigned short* __restrict__ gw,
    float* __restrict__ out)
{
  __shared__ unsigned short X[16 * XSTR];  // [n][k]: 0-63 S_even, 64-127 U, 128-191 S_odd
  __shared__ float sY[64 * YSTR];          // Y transpose buffer [row][ch]

  const int t = threadIdx.x;
  // XCD swizzle: heads 8g..8g+7 (sharing 128B lines of u/y) -> same XCD (i&7)
  const int i = blockIdx.x;
  const int h = ((i & 7) * 4 + ((i >> 3) & 3)) * 8 + (i >> 5);

  const int w    = t >> 6;      // wave id 0..3
  const int lane = t & 63;
  const int n16  = lane & 15;   // MFMA col (Y/S') / B-col
  const int quad = lane >> 4;

  // ---- A-fragments (G rows 32w..32w+31), loaded once from global ----
  const unsigned short* Gh = gw + (size_t)h * 16384;
  short8 A[2][4];
#pragma unroll
  for (int rt = 0; rt < 2; ++rt)
#pragma unroll
    for (int kt = 0; kt < 4; ++kt)
      A[rt][kt] = *(const short8*)(Gh + (32*w + 16*rt + n16)*128 + kt*32 + quad*8);

  // ---- zero X (S_even must be 0; rest harmless) ----
  for (int idx = t; idx < 16*XSTR/2; idx += 256) ((unsigned*)X)[idx] = 0u;
  __syncthreads();

  // ---- U staging assignment: thread t -> col n, 4 k's at m0 ----
  const int n  = t & 15;        // channel = b*4+dd
  const int kq = t >> 4;        // 0..15
  const int m0 = kq * 4;
  const int b  = n >> 2, dd = n & 3;
  const float* up = u + ((size_t)b * SL) * DM + h*4 + dd;

  float ur[4];
#pragma unroll
  for (int j = 0; j < 4; ++j) ur[j] = up[(size_t)(m0 + j) * DM];   // chunk 0

#pragma unroll 1
  for (int q = 0; q < NCHUNK; ++q) {
    // convert + write U half of X
    {
      uint2 pk;
      pk.x = (unsigned)f2bf(ur[0]) | ((unsigned)f2bf(ur[1]) << 16);
      pk.y = (unsigned)f2bf(ur[2]) | ((unsigned)f2bf(ur[3]) << 16);
      *(uint2*)(X + n*XSTR + 64 + m0) = pk;
    }
    __syncthreads();   // B2: U(q) + S(q) visible to all

    // prefetch U(q+1) into registers (overlaps MFMA+epilogue)
    if (q < NCHUNK-1) {
#pragma unroll
      for (int j = 0; j < 4; ++j)
        ur[j] = up[(size_t)((q+1)*KD + m0 + j) * DM];
    }

    const int soff = (q & 1) ? 128 : 0;    // S buffer we read
    const int woff = 128 - soff;           // S buffer we write

    // B-fragments: k-tiles 0,1 = S (parity), 2,3 = U
    const unsigned short* xb = X + n16*XSTR + quad*8;
    short8 B0 = *(const short8*)(xb + soff);
    short8 B1 = *(const short8*)(xb + soff + 32);
    short8 B2 = *(const short8*)(xb + 64);
    short8 B3 = *(const short8*)(xb + 96);

    floatx4 acc0 = {0.f,0.f,0.f,0.f};
    floatx4 acc1 = {0.f,0.f,0.f,0.f};
    acc0 = __builtin_amdgcn_mfma_f32_16x16x32_bf16(A[0][0], B0, acc0, 0,0,0);
    acc1 = __builtin_amdgcn_mfma_f32_16x16x32_bf16(A[1][0], B0, acc1, 0,0,0);
    acc0 = __builtin_amdgcn_mfma_f32_16x16x32_bf16(A[0][1], B1, acc0, 0,0,0);
    acc1 = __builtin_amdgcn_mfma_f32_16x16x32_bf16(A[1][1], B1, acc1, 0,0,0);
    acc0 = __builtin_amdgcn_mfma_f32_16x16x32_bf16(A[0][2], B2, acc0, 0,0,0);
    acc1 = __builtin_amdgcn_mfma_f32_16x16x32_bf16(A[1][2], B2, acc1, 0,0,0);
    acc0 = __builtin_amdgcn_mfma_f32_16x16x32_bf16(A[0][3], B3, acc0, 0,0,0);
    acc1 = __builtin_amdgcn_mfma_f32_16x16x32_bf16(A[1][3], B3, acc1, 0,0,0);

    if (w < 2) {
      // Y rows: scatter into sY (C-layout: col=n16, row=base+quad*4+reg)
#pragma unroll
      for (int reg = 0; reg < 4; ++reg) {
        sY[(32*w +      quad*4 + reg)*YSTR + n16] = acc0[reg];
        sY[(32*w + 16 + quad*4 + reg)*YSTR + n16] = acc1[reg];
      }
    } else {
      // S' rows 64..127 -> bf16 -> X parity buffer (4 consecutive k per quad)
      const int k0 = 32*w + quad*4 - 64;       // rt=0
      uint2 pk;
      pk.x = (unsigned)f2bf(acc0[0]) | ((unsigned)f2bf(acc0[1]) << 16);
      pk.y = (unsigned)f2bf(acc0[2]) | ((unsigned)f2bf(acc0[3]) << 16);
      *(uint2*)(X + n16*XSTR + woff + k0) = pk;
      pk.x = (unsigned)f2bf(acc1[0]) | ((unsigned)f2bf(acc1[1]) << 16);
      pk.y = (unsigned)f2bf(acc1[2]) | ((unsigned)f2bf(acc1[3]) << 16);
      *(uint2*)(X + n16*XSTR + woff + k0 + 16) = pk;
    }
    __syncthreads();   // B3: sY complete, S' committed

    // Y out: thread t -> (row=t>>2, batch=t&3), dwordx4 store
    {
      const int row = t >> 2, bo = t & 3;
      const float4 yv = *(const float4*)(sY + row*YSTR + bo*4);
      *(float4*)(out + ((size_t)bo*SL + (size_t)(q*KD + row))*DM + h*4) = yv;
    }
  }
}

// ---------------------------------------------------------------- launch --
extern "C" void kernel_launch(void* const* d_in, const int* in_sizes, int n_in,
                              void* d_out, int out_size, void* d_ws, size_t ws_size,
                              hipStream_t stream)
{
  const float* u = (const float*)d_in[0];
  const float* a = (const float*)d_in[1];
  const float* b = (const float*)d_in[2];
  const float* c = (const float*)d_in[3];
  unsigned short* gw = (unsigned short*)d_ws;   // 256 * 16384 * 2B = 8 MB
  float* out = (float*)d_out;

  prep_kernel<<<NKH, KD, 0, stream>>>(a, b, c, gw);
  scan_kernel<<<NKH, 256, 0, stream>>>(u, gw, out);
}